// Round 1
// baseline (1592.995 us; speedup 1.0000x reference)
//
#include <hip/hip_runtime.h>
#include <hip/hip_fp16.h>
#include <stdint.h>

// Problem constants
#define TT 4096      // total tokens (B*T)
#define DD 2048      // model dim
#define FF 2048      // expert hidden dim
#define EE 8         // experts
#define BM 128
#define BK 32
#define MAXPAD 9216  // 8192 pairs + 8*128 pad

typedef _Float16 half8 __attribute__((ext_vector_type(8)));
typedef float f32x4 __attribute__((ext_vector_type(4)));

// Direct HBM -> LDS DMA, 16 B per lane, wave-uniform LDS base + lane*16.
__device__ inline void gld_lds16(const _Float16* g, _Float16* l) {
    __builtin_amdgcn_global_load_lds(
        (const __attribute__((address_space(1))) uint32_t*)g,
        (__attribute__((address_space(3))) uint32_t*)l, 16, 0, 0);
}

// XOR swizzle: k-group Q (16B) of tile row R lives at slot Q ^ ((R>>1)&3).
// Staging lane l (row-within-chunk = l>>2, slot = l&3) therefore fetches
// global k-group (l&3) ^ ((l>>3)&3); readers use quad ^ ((row>>1)&3).
// This spreads the 16-lane read phases over all 8 bank quads (2-way = free)
// instead of the unswizzled 8-way conflict on banks {0-3,16-19}.
// (verified: SQ_LDS_BANK_CONFLICT == 0)

// ---------------- utility kernels ----------------

__global__ void zero_cnt_kernel(int* cnt) {
    if (threadIdx.x < EE) cnt[threadIdx.x] = 0;
}

__global__ void cvt_f32_f16_kernel(const float* __restrict__ src,
                                   _Float16* __restrict__ dst, int n) {
    int i = (blockIdx.x * blockDim.x + threadIdx.x) * 4;
    if (i >= n) return;
    float4 v = *(const float4*)(src + i);
    union { _Float16 h[4]; uint2 u; } p;
    p.h[0] = (_Float16)v.x; p.h[1] = (_Float16)v.y;
    p.h[2] = (_Float16)v.z; p.h[3] = (_Float16)v.w;
    *(uint2*)(dst + i) = p.u;
}

// Router: scores = sigmoid(x @ router_DE), top-2, append to per-expert lists.
__global__ void router_topk_kernel(const float* __restrict__ x,
                                   const float* __restrict__ rDE,
                                   int* __restrict__ cnt,
                                   int* __restrict__ tok_list,
                                   float* __restrict__ gate_list) {
    int t = blockIdx.x;
    __shared__ float red[256 * EE];
    float part[EE];
#pragma unroll
    for (int e = 0; e < EE; e++) part[e] = 0.f;
    const float* xr = x + (size_t)t * DD;
    for (int d = threadIdx.x; d < DD; d += 256) {
        float xv = xr[d];
        const float* rr = rDE + (size_t)d * EE;
#pragma unroll
        for (int e = 0; e < EE; e++) part[e] += xv * rr[e];
    }
#pragma unroll
    for (int e = 0; e < EE; e++) red[threadIdx.x * EE + e] = part[e];
    __syncthreads();
    for (int s = 128; s > 0; s >>= 1) {
        if (threadIdx.x < s) {
#pragma unroll
            for (int e = 0; e < EE; e++)
                red[threadIdx.x * EE + e] += red[(threadIdx.x + s) * EE + e];
        }
        __syncthreads();
    }
    if (threadIdx.x == 0) {
        float sc[EE];
#pragma unroll
        for (int e = 0; e < EE; e++) sc[e] = 1.f / (1.f + expf(-red[e]));
        int i0 = 0;
        for (int e = 1; e < EE; e++) if (sc[e] > sc[i0]) i0 = e;
        int i1 = -1;
        for (int e = 0; e < EE; e++) {
            if (e == i0) continue;
            if (i1 < 0 || sc[e] > sc[i1]) i1 = e;
        }
        int p0 = atomicAdd(&cnt[i0], 1);
        tok_list[i0 * TT + p0] = t; gate_list[i0 * TT + p0] = sc[i0];
        int p1 = atomicAdd(&cnt[i1], 1);
        tok_list[i1 * TT + p1] = t; gate_list[i1 * TT + p1] = sc[i1];
    }
}

// Exclusive 128-padded offsets
__global__ void scan_offsets_kernel(const int* __restrict__ cnt, int* __restrict__ poff) {
    if (threadIdx.x == 0) {
        int off = 0;
        for (int e = 0; e < EE; e++) {
            poff[e] = off;
            off += ((cnt[e] + 127) >> 7) << 7;
        }
        poff[EE] = off;
    }
}

// Gather gate-scaled token rows into padded per-expert groups (fp16).
__global__ void gather_rows_kernel(const float* __restrict__ x,
                                   const int* __restrict__ cnt,
                                   const int* __restrict__ poff,
                                   const int* __restrict__ tok_list,
                                   const float* __restrict__ gate_list,
                                   _Float16* __restrict__ gath,
                                   int* __restrict__ rowinfo) {
    int b = blockIdx.x;
    if (b >= poff[EE]) return;
    int e = 0;
    while (b >= poff[e + 1]) e++;
    int i = b - poff[e];
    _Float16* dst = gath + (size_t)b * DD;
    if (i < cnt[e]) {
        int t = tok_list[e * TT + i];
        float g = gate_list[e * TT + i];
        if (threadIdx.x == 0) rowinfo[b] = t;
        const float* src = x + (size_t)t * DD;
        for (int d = threadIdx.x * 4; d < DD; d += 1024) {
            float4 v = *(const float4*)(src + d);
            union { _Float16 h[4]; uint2 u; } p;
            p.h[0] = (_Float16)(v.x * g); p.h[1] = (_Float16)(v.y * g);
            p.h[2] = (_Float16)(v.z * g); p.h[3] = (_Float16)(v.w * g);
            *(uint2*)(dst + d) = p.u;
        }
    } else {
        if (threadIdx.x == 0) rowinfo[b] = -1;
        uint2 z; z.x = 0u; z.y = 0u;
        for (int d = threadIdx.x * 4; d < DD; d += 1024)
            *(uint2*)(dst + d) = z;
    }
}

// ---------------- GEMM kernels ----------------
// C = A(M x 2048) @ W^T pattern: both operands row-major with K contiguous.
// fragment layouts (gfx950, 16x16x32): A/B: elem k = quad*8+j, m/n = lane&15
//                                      C/D: col = lane&15, row = quad*4+reg
//
// Pipeline (T3/T4-minimum): double-buffered LDS, stage tile t+1 BEFORE
// computing tile t, counted s_waitcnt vmcnt(N) so next tile's loads stay in
// flight across both raw s_barriers (no full drain), s_setprio(1) around the
// MFMA cluster. Compiler handles ds_read->MFMA lgkmcnt (ds_reads are
// compiler-visible loads, no inline-asm reads -> rule-18 hazard absent).

// w13 GEMM: computes both halves (y0: W rows [0,F), y1: W rows [F,2F)) and
// writes act = silu(y0)*y1 as fp16.  If cnt!=nullptr: grouped (per-expert) mode.
__global__ __launch_bounds__(256, 2)
void gemm_w13_swiglu_kernel(const _Float16* __restrict__ A,
                            const _Float16* __restrict__ W13,
                            _Float16* __restrict__ act,
                            const int* __restrict__ cnt,
                            const int* __restrict__ poff) {
    int row_base;
    const _Float16* w;
    if (cnt) {
        int e = blockIdx.z;
        int c = cnt[e];
        int mloc = blockIdx.y * BM;
        if (mloc >= c) return;
        row_base = poff[e] + mloc;
        w = W13 + (size_t)e * (2 * FF) * DD;
    } else {
        row_base = blockIdx.y * BM;
        w = W13;
    }
    int n_base = blockIdx.x * 128;

    __shared__ _Float16 lds[2 * 128 * BK * 3];  // 2 x (A | B0 | B1) = 48 KB

    const _Float16* srcA  = A + (size_t)row_base * DD;
    const _Float16* srcB0 = w + (size_t)n_base * DD;
    const _Float16* srcB1 = w + (size_t)(FF + n_base) * DD;

    int lane = threadIdx.x & 63;
    int wv = threadIdx.x >> 6;
    int wm = (wv >> 1) * 64;
    int wn = (wv & 1) * 64;
    int quad = lane >> 4;
    int l15 = lane & 15;
    int ldr = lane >> 2;                                // row-within-chunk for staging
    int ldc = ((lane & 3) ^ ((lane >> 3) & 3)) * 8;     // swizzled source k-group
    int qx = (quad ^ ((l15 >> 1) & 3)) * 8;             // swizzled read slot

    f32x4 acc0[4][4], acc1[4][4];
    f32x4 z4 = {0.f, 0.f, 0.f, 0.f};
#pragma unroll
    for (int m = 0; m < 4; m++)
#pragma unroll
        for (int n = 0; n < 4; n++) { acc0[m][n] = z4; acc1[m][n] = z4; }

    // 24 chunks of 1 KB (A:0-7, B0:8-15, B1:16-23); wave wv takes j*4+wv.
    // 6 gld_lds per wave per tile -> vmcnt granularity 6.
    auto stage = [&](int kt, int slot) {
        int k0 = kt * BK;
        _Float16* dstb = &lds[slot * 12288];
#pragma unroll
        for (int j = 0; j < 6; ++j) {
            int c = j * 4 + wv;
            int tile = c >> 3;
            int lc = c & 7;
            int r = lc * 16 + ldr;
            const _Float16* src = (tile == 0) ? srcA : (tile == 1) ? srcB0 : srcB1;
            gld_lds16(src + (size_t)r * DD + k0 + ldc, dstb + c * 512);
        }
    };

    constexpr int NT = DD / BK;  // 64
    stage(0, 0);
    for (int kt = 0; kt < NT; ++kt) {
        int cur = kt & 1;
        if (kt + 1 < NT) {
            stage(kt + 1, cur ^ 1);                       // 6 more in flight
            asm volatile("s_waitcnt vmcnt(6)" ::: "memory");  // wait tile kt only
        } else {
            asm volatile("s_waitcnt vmcnt(0)" ::: "memory");
        }
        __builtin_amdgcn_s_barrier();                     // raw: no vmem drain
        asm volatile("" ::: "memory");

        const _Float16* lb = &lds[cur * 12288];
        half8 a[4], b0[4], b1[4];
#pragma unroll
        for (int m = 0; m < 4; m++)
            a[m] = *(const half8*)(&lb[(wm + m * 16 + l15) * BK + qx]);
#pragma unroll
        for (int n = 0; n < 4; n++) {
            b0[n] = *(const half8*)(&lb[4096 + (wn + n * 16 + l15) * BK + qx]);
            b1[n] = *(const half8*)(&lb[8192 + (wn + n * 16 + l15) * BK + qx]);
        }
        __builtin_amdgcn_s_setprio(1);
#pragma unroll
        for (int m = 0; m < 4; m++)
#pragma unroll
            for (int n = 0; n < 4; n++) {
                acc0[m][n] = __builtin_amdgcn_mfma_f32_16x16x32_f16(a[m], b0[n], acc0[m][n], 0, 0, 0);
                acc1[m][n] = __builtin_amdgcn_mfma_f32_16x16x32_f16(a[m], b1[n], acc1[m][n], 0, 0, 0);
            }
        __builtin_amdgcn_s_setprio(0);
        asm volatile("" ::: "memory");
        __builtin_amdgcn_s_barrier();                     // frees lds[cur] for kt+2
        asm volatile("" ::: "memory");
    }

#pragma unroll
    for (int m = 0; m < 4; m++)
#pragma unroll
        for (int n = 0; n < 4; n++)
#pragma unroll
            for (int r = 0; r < 4; r++) {
                int row = row_base + wm + m * 16 + quad * 4 + r;
                int col = n_base + wn + n * 16 + l15;
                float y0 = acc0[m][n][r];
                float y1 = acc1[m][n][r];
                float v = y0 / (1.f + __expf(-y0)) * y1;
                act[(size_t)row * FF + col] = (_Float16)v;
            }
}

// w2 GEMM: C = act(M x F) @ W2(N x F)^T -> fp32 out.
// rowinfo==nullptr: plain store with row==token. else: atomicAdd scatter.
__global__ __launch_bounds__(256, 2)
void gemm_w2_kernel(const _Float16* __restrict__ Aact,
                    const _Float16* __restrict__ W2,
                    float* __restrict__ out,
                    const int* __restrict__ cnt,
                    const int* __restrict__ poff,
                    const int* __restrict__ rowinfo) {
    int row_base;
    const _Float16* w;
    if (cnt) {
        int e = blockIdx.z;
        int c = cnt[e];
        int mloc = blockIdx.y * BM;
        if (mloc >= c) return;
        row_base = poff[e] + mloc;
        w = W2 + (size_t)e * DD * FF;
    } else {
        row_base = blockIdx.y * BM;
        w = W2;
    }
    int n_base = blockIdx.x * 128;

    __shared__ _Float16 lds[2 * 128 * BK * 2];  // 2 x (A | B) = 32 KB

    const _Float16* srcA = Aact + (size_t)row_base * FF;
    const _Float16* srcB = w + (size_t)n_base * FF;

    int lane = threadIdx.x & 63;
    int wv = threadIdx.x >> 6;
    int wm = (wv >> 1) * 64;
    int wn = (wv & 1) * 64;
    int quad = lane >> 4;
    int l15 = lane & 15;
    int ldr = lane >> 2;
    int ldc = ((lane & 3) ^ ((lane >> 3) & 3)) * 8;
    int qx = (quad ^ ((l15 >> 1) & 3)) * 8;

    f32x4 acc[4][4];
    f32x4 z4 = {0.f, 0.f, 0.f, 0.f};
#pragma unroll
    for (int m = 0; m < 4; m++)
#pragma unroll
        for (int n = 0; n < 4; n++) acc[m][n] = z4;

    // 16 chunks of 1 KB (A:0-7, B:8-15); 4 gld_lds per wave per tile.
    auto stage = [&](int kt, int slot) {
        int k0 = kt * BK;
        _Float16* dstb = &lds[slot * 8192];
#pragma unroll
        for (int j = 0; j < 4; ++j) {
            int c = j * 4 + wv;
            int tile = c >> 3;
            int lc = c & 7;
            int r = lc * 16 + ldr;
            const _Float16* src = (tile == 0) ? srcA : srcB;
            gld_lds16(src + (size_t)r * FF + k0 + ldc, dstb + c * 512);
        }
    };

    constexpr int NT = FF / BK;  // 64
    stage(0, 0);
    for (int kt = 0; kt < NT; ++kt) {
        int cur = kt & 1;
        if (kt + 1 < NT) {
            stage(kt + 1, cur ^ 1);
            asm volatile("s_waitcnt vmcnt(4)" ::: "memory");  // wait tile kt only
        } else {
            asm volatile("s_waitcnt vmcnt(0)" ::: "memory");
        }
        __builtin_amdgcn_s_barrier();
        asm volatile("" ::: "memory");

        const _Float16* lb = &lds[cur * 8192];
        half8 a[4], b[4];
#pragma unroll
        for (int m = 0; m < 4; m++)
            a[m] = *(const half8*)(&lb[(wm + m * 16 + l15) * BK + qx]);
#pragma unroll
        for (int n = 0; n < 4; n++)
            b[n] = *(const half8*)(&lb[4096 + (wn + n * 16 + l15) * BK + qx]);
        __builtin_amdgcn_s_setprio(1);
#pragma unroll
        for (int m = 0; m < 4; m++)
#pragma unroll
            for (int n = 0; n < 4; n++)
                acc[m][n] = __builtin_amdgcn_mfma_f32_16x16x32_f16(a[m], b[n], acc[m][n], 0, 0, 0);
        __builtin_amdgcn_s_setprio(0);
        asm volatile("" ::: "memory");
        __builtin_amdgcn_s_barrier();
        asm volatile("" ::: "memory");
    }

#pragma unroll
    for (int m = 0; m < 4; m++)
#pragma unroll
        for (int n = 0; n < 4; n++)
#pragma unroll
            for (int r = 0; r < 4; r++) {
                int row = row_base + wm + m * 16 + quad * 4 + r;
                int col = n_base + wn + n * 16 + l15;
                float v = acc[m][n][r];
                if (rowinfo) {
                    int t = rowinfo[row];
                    if (t >= 0) atomicAdd(&out[(size_t)t * DD + col], v);
                } else {
                    out[(size_t)row * DD + col] = v;
                }
            }
}

// ---------------- launch ----------------

extern "C" void kernel_launch(void* const* d_in, const int* in_sizes, int n_in,
                              void* d_out, int out_size, void* d_ws, size_t ws_size,
                              hipStream_t stream) {
    const float* x     = (const float*)d_in[0];   // 4096 x 2048
    const float* rDE   = (const float*)d_in[1];   // 2048 x 8
    const float* sw13  = (const float*)d_in[2];   // 4096 x 2048
    const float* sw2   = (const float*)d_in[3];   // 2048 x 2048
    const float* rw13  = (const float*)d_in[4];   // 8 x 4096 x 2048
    const float* rw2   = (const float*)d_in[5];   // 8 x 2048 x 2048
    float* out = (float*)d_out;

    char* ws = (char*)d_ws;
    size_t off = 0;
    auto alloc = [&](size_t bytes) {
        char* p = ws + off;
        off += (bytes + 255) & ~(size_t)255;
        return p;
    };
    _Float16* xh    = (_Float16*)alloc((size_t)TT * DD * 2);
    _Float16* sw13h = (_Float16*)alloc((size_t)2 * FF * DD * 2);
    _Float16* sw2h  = (_Float16*)alloc((size_t)DD * FF * 2);
    _Float16* rw13h = (_Float16*)alloc((size_t)EE * 2 * FF * DD * 2);
    _Float16* rw2h  = (_Float16*)alloc((size_t)EE * DD * FF * 2);
    _Float16* acts  = (_Float16*)alloc((size_t)TT * FF * 2);
    _Float16* gath  = (_Float16*)alloc((size_t)MAXPAD * DD * 2);
    _Float16* actr  = (_Float16*)alloc((size_t)MAXPAD * FF * 2);
    int* cnt        = (int*)alloc(EE * 4);
    int* poff       = (int*)alloc((EE + 1) * 4);
    int* tok_list   = (int*)alloc((size_t)EE * TT * 4);
    float* gate_list= (float*)alloc((size_t)EE * TT * 4);
    int* rowinfo    = (int*)alloc((size_t)MAXPAD * 4);

    zero_cnt_kernel<<<1, 64, 0, stream>>>(cnt);

    // fp32 -> fp16 conversions
    auto cvt = [&](const float* s, _Float16* d, int n) {
        cvt_f32_f16_kernel<<<(n / 4 + 255) / 256, 256, 0, stream>>>(s, d, n);
    };
    cvt(x,    xh,    TT * DD);
    cvt(sw13, sw13h, 2 * FF * DD);
    cvt(sw2,  sw2h,  DD * FF);
    cvt(rw13, rw13h, EE * 2 * FF * DD);
    cvt(rw2,  rw2h,  EE * DD * FF);

    router_topk_kernel<<<TT, 256, 0, stream>>>(x, rDE, cnt, tok_list, gate_list);
    scan_offsets_kernel<<<1, 64, 0, stream>>>(cnt, poff);
    gather_rows_kernel<<<MAXPAD, 256, 0, stream>>>(x, cnt, poff, tok_list, gate_list,
                                                   gath, rowinfo);

    // shared expert
    gemm_w13_swiglu_kernel<<<dim3(FF / 128, TT / 128, 1), 256, 0, stream>>>(
        xh, sw13h, acts, nullptr, nullptr);
    gemm_w2_kernel<<<dim3(DD / 128, TT / 128, 1), 256, 0, stream>>>(
        acts, sw2h, out, nullptr, nullptr, nullptr);

    // routed experts (grouped, early-exit tiles), scatter-add on top of shared out
    gemm_w13_swiglu_kernel<<<dim3(FF / 128, TT / 128, EE), 256, 0, stream>>>(
        gath, rw13h, actr, cnt, poff);
    gemm_w2_kernel<<<dim3(DD / 128, TT / 128, EE), 256, 0, stream>>>(
        actr, rw2h, out, cnt, poff, rowinfo);
}

// Round 2
// 1264.055 us; speedup vs baseline: 1.2602x; 1.2602x over previous
//
#include <hip/hip_runtime.h>
#include <hip/hip_fp16.h>
#include <stdint.h>

// Problem constants
#define TT 4096      // total tokens (B*T)
#define DD 2048      // model dim
#define FF 2048      // expert hidden dim
#define EE 8         // experts
#define BM 128
#define BK 32
#define MAXPAD 9216  // 8192 pairs + 8*128 pad

typedef _Float16 half8 __attribute__((ext_vector_type(8)));
typedef float f32x4 __attribute__((ext_vector_type(4)));

// Direct HBM -> LDS DMA, 16 B per lane, wave-uniform LDS base + lane*16.
__device__ inline void gld_lds16(const _Float16* g, _Float16* l) {
    __builtin_amdgcn_global_load_lds(
        (const __attribute__((address_space(1))) uint32_t*)g,
        (__attribute__((address_space(3))) uint32_t*)l, 16, 0, 0);
}

// XOR swizzle: k-group Q (16B) of tile row R lives at slot Q ^ ((R>>1)&3).
// Staging lane l (row-within-chunk = l>>2, slot = l&3) therefore fetches
// global k-group (l&3) ^ ((l>>3)&3); readers use quad ^ ((row>>1)&3).
// (verified: SQ_LDS_BANK_CONFLICT == 0)
//
// NOTE (round-1 post-mortem): double-buffered LDS + inline-asm counted vmcnt
// REGRESSED 2.5x here — the compiler cannot prove dbuf disjointness and
// inserts its own vmcnt(0) before the dependent ds_reads, serializing the
// prefetch while the per-iteration "memory" clobbers defeat its scheduling
// (m141 failure mode). The 2-barrier __syncthreads structure is kept.
// This round's lever instead: keep ONE accumulator set per kernel (64 AGPR)
// so 3 waves/SIMD fit, matching m97's proven config.

// ---------------- utility kernels ----------------

__global__ void zero_cnt_kernel(int* cnt) {
    if (threadIdx.x < EE) cnt[threadIdx.x] = 0;
}

__global__ void cvt_f32_f16_kernel(const float* __restrict__ src,
                                   _Float16* __restrict__ dst, int n) {
    int i = (blockIdx.x * blockDim.x + threadIdx.x) * 4;
    if (i >= n) return;
    float4 v = *(const float4*)(src + i);
    union { _Float16 h[4]; uint2 u; } p;
    p.h[0] = (_Float16)v.x; p.h[1] = (_Float16)v.y;
    p.h[2] = (_Float16)v.z; p.h[3] = (_Float16)v.w;
    *(uint2*)(dst + i) = p.u;
}

// Router: scores = sigmoid(x @ router_DE), top-2, append to per-expert lists.
__global__ void router_topk_kernel(const float* __restrict__ x,
                                   const float* __restrict__ rDE,
                                   int* __restrict__ cnt,
                                   int* __restrict__ tok_list,
                                   float* __restrict__ gate_list) {
    int t = blockIdx.x;
    __shared__ float red[256 * EE];
    float part[EE];
#pragma unroll
    for (int e = 0; e < EE; e++) part[e] = 0.f;
    const float* xr = x + (size_t)t * DD;
    for (int d = threadIdx.x; d < DD; d += 256) {
        float xv = xr[d];
        const float* rr = rDE + (size_t)d * EE;
#pragma unroll
        for (int e = 0; e < EE; e++) part[e] += xv * rr[e];
    }
#pragma unroll
    for (int e = 0; e < EE; e++) red[threadIdx.x * EE + e] = part[e];
    __syncthreads();
    for (int s = 128; s > 0; s >>= 1) {
        if (threadIdx.x < s) {
#pragma unroll
            for (int e = 0; e < EE; e++)
                red[threadIdx.x * EE + e] += red[(threadIdx.x + s) * EE + e];
        }
        __syncthreads();
    }
    if (threadIdx.x == 0) {
        float sc[EE];
#pragma unroll
        for (int e = 0; e < EE; e++) sc[e] = 1.f / (1.f + expf(-red[e]));
        int i0 = 0;
        for (int e = 1; e < EE; e++) if (sc[e] > sc[i0]) i0 = e;
        int i1 = -1;
        for (int e = 0; e < EE; e++) {
            if (e == i0) continue;
            if (i1 < 0 || sc[e] > sc[i1]) i1 = e;
        }
        int p0 = atomicAdd(&cnt[i0], 1);
        tok_list[i0 * TT + p0] = t; gate_list[i0 * TT + p0] = sc[i0];
        int p1 = atomicAdd(&cnt[i1], 1);
        tok_list[i1 * TT + p1] = t; gate_list[i1 * TT + p1] = sc[i1];
    }
}

// Exclusive 128-padded offsets
__global__ void scan_offsets_kernel(const int* __restrict__ cnt, int* __restrict__ poff) {
    if (threadIdx.x == 0) {
        int off = 0;
        for (int e = 0; e < EE; e++) {
            poff[e] = off;
            off += ((cnt[e] + 127) >> 7) << 7;
        }
        poff[EE] = off;
    }
}

// Gather gate-scaled token rows into padded per-expert groups (fp16).
__global__ void gather_rows_kernel(const float* __restrict__ x,
                                   const int* __restrict__ cnt,
                                   const int* __restrict__ poff,
                                   const int* __restrict__ tok_list,
                                   const float* __restrict__ gate_list,
                                   _Float16* __restrict__ gath,
                                   int* __restrict__ rowinfo) {
    int b = blockIdx.x;
    if (b >= poff[EE]) return;
    int e = 0;
    while (b >= poff[e + 1]) e++;
    int i = b - poff[e];
    _Float16* dst = gath + (size_t)b * DD;
    if (i < cnt[e]) {
        int t = tok_list[e * TT + i];
        float g = gate_list[e * TT + i];
        if (threadIdx.x == 0) rowinfo[b] = t;
        const float* src = x + (size_t)t * DD;
        for (int d = threadIdx.x * 4; d < DD; d += 1024) {
            float4 v = *(const float4*)(src + d);
            union { _Float16 h[4]; uint2 u; } p;
            p.h[0] = (_Float16)(v.x * g); p.h[1] = (_Float16)(v.y * g);
            p.h[2] = (_Float16)(v.z * g); p.h[3] = (_Float16)(v.w * g);
            *(uint2*)(dst + d) = p.u;
        }
    } else {
        if (threadIdx.x == 0) rowinfo[b] = -1;
        uint2 z; z.x = 0u; z.y = 0u;
        for (int d = threadIdx.x * 4; d < DD; d += 1024)
            *(uint2*)(dst + d) = z;
    }
}

// ---------------- GEMM kernels ----------------
// C = A(M x 2048) @ W^T pattern: both operands row-major with K=2048 contiguous.
// fragment layouts (gfx950, 16x16x32): A/B: elem k = quad*8+j, m/n = lane&15
//                                      C/D: col = lane&15, row = quad*4+reg

// One w13 HALF: C = A @ Whalf^T (Whalf: FF rows x DD cols).
//   mode 0: act = silu(C)        (fp16 store)
//   mode 1: act = act * C        (in-place RMW, disjoint per lane)
// If cnt!=nullptr: grouped (per-expert) mode; w = W + e*estride.
__global__ __launch_bounds__(256, 2)
void gemm_w13_half_kernel(const _Float16* __restrict__ A,
                          const _Float16* __restrict__ W,
                          _Float16* __restrict__ act,
                          int mode,
                          const int* __restrict__ cnt,
                          const int* __restrict__ poff,
                          size_t estride) {
    int row_base;
    const _Float16* w;
    if (cnt) {
        int e = blockIdx.z;
        int c = cnt[e];
        int mloc = blockIdx.y * BM;
        if (mloc >= c) return;
        row_base = poff[e] + mloc;
        w = W + (size_t)e * estride;
    } else {
        row_base = blockIdx.y * BM;
        w = W;
    }
    int n_base = blockIdx.x * 128;

    __shared__ _Float16 lds[128 * BK * 2];  // A | B = 16 KB

    const _Float16* srcA = A + (size_t)row_base * DD;
    const _Float16* srcB = w + (size_t)n_base * DD;

    int lane = threadIdx.x & 63;
    int wv = threadIdx.x >> 6;
    int wm = (wv >> 1) * 64;
    int wn = (wv & 1) * 64;
    int quad = lane >> 4;
    int l15 = lane & 15;
    int ldr = lane >> 2;
    int ldc = ((lane & 3) ^ ((lane >> 3) & 3)) * 8;
    int qx = (quad ^ ((l15 >> 1) & 3)) * 8;

    f32x4 acc[4][4];
    f32x4 z4 = {0.f, 0.f, 0.f, 0.f};
#pragma unroll
    for (int m = 0; m < 4; m++)
#pragma unroll
        for (int n = 0; n < 4; n++) acc[m][n] = z4;

    for (int kt = 0; kt < DD / BK; ++kt) {
        int k0 = kt * BK;
        // 16 chunks of 1 KB (A:0-7, B:8-15); wave wv takes j*4+wv
#pragma unroll
        for (int j = 0; j < 4; ++j) {
            int c = j * 4 + wv;
            int tile = c >> 3;
            int lc = c & 7;
            int r = lc * 16 + ldr;
            const _Float16* src = (tile == 0) ? srcA : srcB;
            gld_lds16(src + (size_t)r * DD + k0 + ldc, &lds[c * 512]);
        }
        __syncthreads();

        half8 a[4], b[4];
#pragma unroll
        for (int m = 0; m < 4; m++)
            a[m] = *(const half8*)(&lds[(wm + m * 16 + l15) * BK + qx]);
#pragma unroll
        for (int n = 0; n < 4; n++)
            b[n] = *(const half8*)(&lds[4096 + (wn + n * 16 + l15) * BK + qx]);
#pragma unroll
        for (int m = 0; m < 4; m++)
#pragma unroll
            for (int n = 0; n < 4; n++)
                acc[m][n] = __builtin_amdgcn_mfma_f32_16x16x32_f16(a[m], b[n], acc[m][n], 0, 0, 0);
        __syncthreads();
    }

#pragma unroll
    for (int m = 0; m < 4; m++)
#pragma unroll
        for (int n = 0; n < 4; n++)
#pragma unroll
            for (int r = 0; r < 4; r++) {
                int row = row_base + wm + m * 16 + quad * 4 + r;
                int col = n_base + wn + n * 16 + l15;
                size_t idx = (size_t)row * FF + col;
                float v = acc[m][n][r];
                if (mode == 0) {
                    act[idx] = (_Float16)(v / (1.f + __expf(-v)));
                } else {
                    float t = (float)act[idx];
                    act[idx] = (_Float16)(t * v);
                }
            }
}

// w2 GEMM: C = act(M x F) @ W2(N x F)^T -> fp32 out.
// rowinfo==nullptr: plain store with row==token. else: atomicAdd scatter.
__global__ __launch_bounds__(256, 2)
void gemm_w2_kernel(const _Float16* __restrict__ Aact,
                    const _Float16* __restrict__ W2,
                    float* __restrict__ out,
                    const int* __restrict__ cnt,
                    const int* __restrict__ poff,
                    const int* __restrict__ rowinfo) {
    int row_base;
    const _Float16* w;
    if (cnt) {
        int e = blockIdx.z;
        int c = cnt[e];
        int mloc = blockIdx.y * BM;
        if (mloc >= c) return;
        row_base = poff[e] + mloc;
        w = W2 + (size_t)e * DD * FF;
    } else {
        row_base = blockIdx.y * BM;
        w = W2;
    }
    int n_base = blockIdx.x * 128;

    __shared__ _Float16 lds[128 * BK * 2];  // A | B = 16 KB

    const _Float16* srcA = Aact + (size_t)row_base * FF;
    const _Float16* srcB = w + (size_t)n_base * FF;

    int lane = threadIdx.x & 63;
    int wv = threadIdx.x >> 6;
    int wm = (wv >> 1) * 64;
    int wn = (wv & 1) * 64;
    int quad = lane >> 4;
    int l15 = lane & 15;
    int ldr = lane >> 2;
    int ldc = ((lane & 3) ^ ((lane >> 3) & 3)) * 8;
    int qx = (quad ^ ((l15 >> 1) & 3)) * 8;

    f32x4 acc[4][4];
    f32x4 z4 = {0.f, 0.f, 0.f, 0.f};
#pragma unroll
    for (int m = 0; m < 4; m++)
#pragma unroll
        for (int n = 0; n < 4; n++) acc[m][n] = z4;

    for (int kt = 0; kt < FF / BK; ++kt) {
        int k0 = kt * BK;
        // 16 chunks of 1 KB (A:0-7, B:8-15); wave wv takes j*4+wv
#pragma unroll
        for (int j = 0; j < 4; ++j) {
            int c = j * 4 + wv;
            int tile = c >> 3;
            int lc = c & 7;
            int r = lc * 16 + ldr;
            const _Float16* src = (tile == 0) ? srcA : srcB;
            gld_lds16(src + (size_t)r * FF + k0 + ldc, &lds[c * 512]);
        }
        __syncthreads();

        half8 a[4], b[4];
#pragma unroll
        for (int m = 0; m < 4; m++)
            a[m] = *(const half8*)(&lds[(wm + m * 16 + l15) * BK + qx]);
#pragma unroll
        for (int n = 0; n < 4; n++)
            b[n] = *(const half8*)(&lds[4096 + (wn + n * 16 + l15) * BK + qx]);
#pragma unroll
        for (int m = 0; m < 4; m++)
#pragma unroll
            for (int n = 0; n < 4; n++)
                acc[m][n] = __builtin_amdgcn_mfma_f32_16x16x32_f16(a[m], b[n], acc[m][n], 0, 0, 0);
        __syncthreads();
    }

#pragma unroll
    for (int m = 0; m < 4; m++)
#pragma unroll
        for (int n = 0; n < 4; n++)
#pragma unroll
            for (int r = 0; r < 4; r++) {
                int row = row_base + wm + m * 16 + quad * 4 + r;
                int col = n_base + wn + n * 16 + l15;
                float v = acc[m][n][r];
                if (rowinfo) {
                    int t = rowinfo[row];
                    if (t >= 0) atomicAdd(&out[(size_t)t * DD + col], v);
                } else {
                    out[(size_t)row * DD + col] = v;
                }
            }
}

// ---------------- launch ----------------

extern "C" void kernel_launch(void* const* d_in, const int* in_sizes, int n_in,
                              void* d_out, int out_size, void* d_ws, size_t ws_size,
                              hipStream_t stream) {
    const float* x     = (const float*)d_in[0];   // 4096 x 2048
    const float* rDE   = (const float*)d_in[1];   // 2048 x 8
    const float* sw13  = (const float*)d_in[2];   // 4096 x 2048
    const float* sw2   = (const float*)d_in[3];   // 2048 x 2048
    const float* rw13  = (const float*)d_in[4];   // 8 x 4096 x 2048
    const float* rw2   = (const float*)d_in[5];   // 8 x 2048 x 2048
    float* out = (float*)d_out;

    char* ws = (char*)d_ws;
    size_t off = 0;
    auto alloc = [&](size_t bytes) {
        char* p = ws + off;
        off += (bytes + 255) & ~(size_t)255;
        return p;
    };
    _Float16* xh    = (_Float16*)alloc((size_t)TT * DD * 2);
    _Float16* sw13h = (_Float16*)alloc((size_t)2 * FF * DD * 2);
    _Float16* sw2h  = (_Float16*)alloc((size_t)DD * FF * 2);
    _Float16* rw13h = (_Float16*)alloc((size_t)EE * 2 * FF * DD * 2);
    _Float16* rw2h  = (_Float16*)alloc((size_t)EE * DD * FF * 2);
    _Float16* acts  = (_Float16*)alloc((size_t)TT * FF * 2);
    _Float16* gath  = (_Float16*)alloc((size_t)MAXPAD * DD * 2);
    _Float16* actr  = (_Float16*)alloc((size_t)MAXPAD * FF * 2);
    int* cnt        = (int*)alloc(EE * 4);
    int* poff       = (int*)alloc((EE + 1) * 4);
    int* tok_list   = (int*)alloc((size_t)EE * TT * 4);
    float* gate_list= (float*)alloc((size_t)EE * TT * 4);
    int* rowinfo    = (int*)alloc((size_t)MAXPAD * 4);

    zero_cnt_kernel<<<1, 64, 0, stream>>>(cnt);

    // fp32 -> fp16 conversions
    auto cvt = [&](const float* s, _Float16* d, int n) {
        cvt_f32_f16_kernel<<<(n / 4 + 255) / 256, 256, 0, stream>>>(s, d, n);
    };
    cvt(x,    xh,    TT * DD);
    cvt(sw13, sw13h, 2 * FF * DD);
    cvt(sw2,  sw2h,  DD * FF);
    cvt(rw13, rw13h, EE * 2 * FF * DD);
    cvt(rw2,  rw2h,  EE * DD * FF);

    router_topk_kernel<<<TT, 256, 0, stream>>>(x, rDE, cnt, tok_list, gate_list);
    scan_offsets_kernel<<<1, 64, 0, stream>>>(cnt, poff);
    gather_rows_kernel<<<MAXPAD, 256, 0, stream>>>(x, cnt, poff, tok_list, gate_list,
                                                   gath, rowinfo);

    const size_t w13_half_off = (size_t)FF * DD;      // offset of W3 within w13
    const size_t w13_estride  = (size_t)2 * FF * DD;  // per-expert stride

    // shared expert: act = silu(x@W1^T); act *= x@W3^T; out = act@W2^T
    gemm_w13_half_kernel<<<dim3(FF / 128, TT / 128, 1), 256, 0, stream>>>(
        xh, sw13h, acts, 0, nullptr, nullptr, 0);
    gemm_w13_half_kernel<<<dim3(FF / 128, TT / 128, 1), 256, 0, stream>>>(
        xh, sw13h + w13_half_off, acts, 1, nullptr, nullptr, 0);
    gemm_w2_kernel<<<dim3(DD / 128, TT / 128, 1), 256, 0, stream>>>(
        acts, sw2h, out, nullptr, nullptr, nullptr);

    // routed experts (grouped, early-exit tiles), scatter-add on top of shared out
    gemm_w13_half_kernel<<<dim3(FF / 128, TT / 128, EE), 256, 0, stream>>>(
        gath, rw13h, actr, 0, cnt, poff, w13_estride);
    gemm_w13_half_kernel<<<dim3(FF / 128, TT / 128, EE), 256, 0, stream>>>(
        gath, rw13h + w13_half_off, actr, 1, cnt, poff, w13_estride);
    gemm_w2_kernel<<<dim3(DD / 128, TT / 128, EE), 256, 0, stream>>>(
        actr, rw2h, out, cnt, poff, rowinfo);
}

// Round 3
// 1028.097 us; speedup vs baseline: 1.5495x; 1.2295x over previous
//
#include <hip/hip_runtime.h>
#include <hip/hip_fp16.h>
#include <stdint.h>

// Problem constants
#define TT 4096      // total tokens (B*T)
#define DD 2048      // model dim
#define FF 2048      // expert hidden dim
#define EE 8         // experts
#define BM 128
#define BK 64        // K-tile (round 3: 32 -> 64, halves barrier count)
#define MAXPAD 9216  // 8192 pairs + 8*128 pad

typedef _Float16 half8 __attribute__((ext_vector_type(8)));
typedef float f32x4 __attribute__((ext_vector_type(4)));

// Direct HBM -> LDS DMA, 16 B per lane, wave-uniform LDS base + lane*16.
__device__ inline void gld_lds16(const _Float16* g, _Float16* l) {
    __builtin_amdgcn_global_load_lds(
        (const __attribute__((address_space(1))) uint32_t*)g,
        (__attribute__((address_space(3))) uint32_t*)l, 16, 0, 0);
}

// BK=64 XOR swizzle: a tile row is 128 B (all 32 banks); 16-B k-group g of
// row r lives at physical slot g ^ (r & 7).  Staging lane l (chunk row =
// l>>3, phys slot = l&7) fetches global k-group (l&7) ^ ((l>>3)&7).  A
// 16-lane read phase (one quad, rows r..r+15, same logical slot) then maps
// to 8 distinct slots x 2 rows = 2-way bank aliasing = free (m136).
//
// Round-1 post-mortem: dbuf + inline-asm counted vmcnt regressed 2.5x
// (compiler re-drains vmcnt(0); per-iter "memory" clobbers pin the
// scheduler - m141 failure mode).  Keep the proven 2-barrier loop.
// Round-2 post-mortem: MfmaUtil scales with MFMA per barrier-pair
// (32 MFMA -> 27%, 16 MFMA -> 15%), NOT with occupancy.  So: fused-width
// tiles everywhere (128x256 output work, 128 acc regs) + BK=64.

// ---------------- utility kernels ----------------

__global__ void zero_cnt_kernel(int* cnt) {
    if (threadIdx.x < EE) cnt[threadIdx.x] = 0;
}

__global__ void cvt_f32_f16_kernel(const float* __restrict__ src,
                                   _Float16* __restrict__ dst, int n) {
    int i = (blockIdx.x * blockDim.x + threadIdx.x) * 4;
    if (i >= n) return;
    float4 v = *(const float4*)(src + i);
    union { _Float16 h[4]; uint2 u; } p;
    p.h[0] = (_Float16)v.x; p.h[1] = (_Float16)v.y;
    p.h[2] = (_Float16)v.z; p.h[3] = (_Float16)v.w;
    *(uint2*)(dst + i) = p.u;
}

// Router: scores = sigmoid(x @ router_DE), top-2, append to per-expert lists.
// Also records per-token (e0,p0,e1,p1) so the combine pass needs no atomics.
__global__ void router_topk_kernel(const float* __restrict__ x,
                                   const float* __restrict__ rDE,
                                   int* __restrict__ cnt,
                                   int* __restrict__ tok_list,
                                   float* __restrict__ gate_list,
                                   int4* __restrict__ meta) {
    int t = blockIdx.x;
    __shared__ float red[256 * EE];
    float part[EE];
#pragma unroll
    for (int e = 0; e < EE; e++) part[e] = 0.f;
    const float* xr = x + (size_t)t * DD;
    for (int d = threadIdx.x; d < DD; d += 256) {
        float xv = xr[d];
        const float* rr = rDE + (size_t)d * EE;
#pragma unroll
        for (int e = 0; e < EE; e++) part[e] += xv * rr[e];
    }
#pragma unroll
    for (int e = 0; e < EE; e++) red[threadIdx.x * EE + e] = part[e];
    __syncthreads();
    for (int s = 128; s > 0; s >>= 1) {
        if (threadIdx.x < s) {
#pragma unroll
            for (int e = 0; e < EE; e++)
                red[threadIdx.x * EE + e] += red[(threadIdx.x + s) * EE + e];
        }
        __syncthreads();
    }
    if (threadIdx.x == 0) {
        float sc[EE];
#pragma unroll
        for (int e = 0; e < EE; e++) sc[e] = 1.f / (1.f + expf(-red[e]));
        int i0 = 0;
        for (int e = 1; e < EE; e++) if (sc[e] > sc[i0]) i0 = e;
        int i1 = -1;
        for (int e = 0; e < EE; e++) {
            if (e == i0) continue;
            if (i1 < 0 || sc[e] > sc[i1]) i1 = e;
        }
        int p0 = atomicAdd(&cnt[i0], 1);
        tok_list[i0 * TT + p0] = t; gate_list[i0 * TT + p0] = sc[i0];
        int p1 = atomicAdd(&cnt[i1], 1);
        tok_list[i1 * TT + p1] = t; gate_list[i1 * TT + p1] = sc[i1];
        meta[t] = make_int4(i0, p0, i1, p1);
    }
}

// Exclusive 128-padded offsets
__global__ void scan_offsets_kernel(const int* __restrict__ cnt, int* __restrict__ poff) {
    if (threadIdx.x == 0) {
        int off = 0;
        for (int e = 0; e < EE; e++) {
            poff[e] = off;
            off += ((cnt[e] + 127) >> 7) << 7;
        }
        poff[EE] = off;
    }
}

// Gather gate-scaled token rows into padded per-expert groups (fp16).
__global__ void gather_rows_kernel(const float* __restrict__ x,
                                   const int* __restrict__ cnt,
                                   const int* __restrict__ poff,
                                   const int* __restrict__ tok_list,
                                   const float* __restrict__ gate_list,
                                   _Float16* __restrict__ gath) {
    int b = blockIdx.x;
    if (b >= poff[EE]) return;
    int e = 0;
    while (b >= poff[e + 1]) e++;
    int i = b - poff[e];
    _Float16* dst = gath + (size_t)b * DD;
    if (i < cnt[e]) {
        int t = tok_list[e * TT + i];
        float g = gate_list[e * TT + i];
        const float* src = x + (size_t)t * DD;
        for (int d = threadIdx.x * 4; d < DD; d += 1024) {
            float4 v = *(const float4*)(src + d);
            union { _Float16 h[4]; uint2 u; } p;
            p.h[0] = (_Float16)(v.x * g); p.h[1] = (_Float16)(v.y * g);
            p.h[2] = (_Float16)(v.z * g); p.h[3] = (_Float16)(v.w * g);
            *(uint2*)(dst + d) = p.u;
        }
    } else {
        uint2 z; z.x = 0u; z.y = 0u;
        for (int d = threadIdx.x * 4; d < DD; d += 1024)
            *(uint2*)(dst + d) = z;
    }
}

// ---------------- GEMM kernels ----------------
// C = A(M x 2048) @ W^T: both operands row-major, K contiguous.
// fragment layouts (gfx950, 16x16x32): A/B: elem k = quad*8+j, m/n = lane&15
//                                      C/D: col = lane&15, row = quad*4+reg

// Fused w13 (z = 0..7 routed expert z, z = 8 shared):
//   act = silu(A@W1^T) * (A@W3^T), fp16, 128x128 output tile (x2 halves).
__global__ __launch_bounds__(256, 2)
void gemm_w13_kernel(const _Float16* __restrict__ xh,
                     const _Float16* __restrict__ gath,
                     const _Float16* __restrict__ sw13,
                     const _Float16* __restrict__ rw13,
                     _Float16* __restrict__ acts,
                     _Float16* __restrict__ actr,
                     const int* __restrict__ cnt,
                     const int* __restrict__ poff) {
    int z = blockIdx.z;
    const _Float16 *srcA, *w;
    _Float16* dst;
    if (z == EE) {
        srcA = xh + (size_t)blockIdx.y * BM * DD;
        w = sw13;
        dst = acts + (size_t)blockIdx.y * BM * FF;
    } else {
        int c = cnt[z];
        int mloc = blockIdx.y * BM;
        if (mloc >= c) return;
        int rb = poff[z] + mloc;
        srcA = gath + (size_t)rb * DD;
        w = rw13 + (size_t)z * (2 * FF) * DD;
        dst = actr + (size_t)rb * FF;
    }
    int n_base = blockIdx.x * 128;

    __shared__ _Float16 lds[3 * 128 * BK];  // A | B0 | B1 = 48 KB

    const _Float16* srcB0 = w + (size_t)n_base * DD;
    const _Float16* srcB1 = w + (size_t)(FF + n_base) * DD;

    int lane = threadIdx.x & 63;
    int wv = threadIdx.x >> 6;
    int wm = (wv >> 1) * 64;
    int wn = (wv & 1) * 64;
    int quad = lane >> 4;
    int l15 = lane & 15;
    int srow = lane >> 3;                        // row-within-chunk (8 rows/chunk)
    int sk = ((lane & 7) ^ srow) * 8;            // swizzled source k-offset (halves)

    f32x4 acc0[4][4], acc1[4][4];
    f32x4 z4 = {0.f, 0.f, 0.f, 0.f};
#pragma unroll
    for (int m = 0; m < 4; m++)
#pragma unroll
        for (int n = 0; n < 4; n++) { acc0[m][n] = z4; acc1[m][n] = z4; }

    for (int kt = 0; kt < DD / BK; ++kt) {       // 32 iterations
        int k0 = kt * BK;
        // 48 chunks of 1 KB (A:0-15, B0:16-31, B1:32-47); wave wv takes j*4+wv
#pragma unroll
        for (int j = 0; j < 12; ++j) {
            int c = j * 4 + wv;
            int tile = c >> 4;
            int lc = c & 15;
            int r = lc * 8 + srow;
            const _Float16* src = (tile == 0) ? srcA : (tile == 1) ? srcB0 : srcB1;
            gld_lds16(src + (size_t)r * DD + k0 + sk, &lds[c * 512]);
        }
        __syncthreads();

#pragma unroll
        for (int ks = 0; ks < 2; ++ks) {
            half8 a[4], b0[4], b1[4];
#pragma unroll
            for (int m = 0; m < 4; m++) {
                int ra = wm + m * 16 + l15;
                a[m] = *(const half8*)(&lds[ra * BK + (((ks * 4 + quad) ^ (ra & 7)) * 8)]);
            }
#pragma unroll
            for (int n = 0; n < 4; n++) {
                int rb = wn + n * 16 + l15;
                int px = ((ks * 4 + quad) ^ (rb & 7)) * 8;
                b0[n] = *(const half8*)(&lds[8192 + rb * BK + px]);
                b1[n] = *(const half8*)(&lds[16384 + rb * BK + px]);
            }
#pragma unroll
            for (int m = 0; m < 4; m++)
#pragma unroll
                for (int n = 0; n < 4; n++) {
                    acc0[m][n] = __builtin_amdgcn_mfma_f32_16x16x32_f16(a[m], b0[n], acc0[m][n], 0, 0, 0);
                    acc1[m][n] = __builtin_amdgcn_mfma_f32_16x16x32_f16(a[m], b1[n], acc1[m][n], 0, 0, 0);
                }
        }
        __syncthreads();
    }

#pragma unroll
    for (int m = 0; m < 4; m++)
#pragma unroll
        for (int n = 0; n < 4; n++)
#pragma unroll
            for (int r = 0; r < 4; r++) {
                int row = wm + m * 16 + quad * 4 + r;
                int col = n_base + wn + n * 16 + l15;
                float y0 = acc0[m][n][r];
                float y1 = acc1[m][n][r];
                float v = y0 / (1.f + __expf(-y0)) * y1;
                dst[(size_t)row * FF + col] = (_Float16)v;
            }
}

// w2 GEMM (z = 0..7 routed -> zr slots, z = 8 shared -> out), 128M x 256N
// tile, 4 waves each 64x128, acc[4][8] = 128 regs, 64 MFMA/iteration/wave.
// Plain coalesced fp32 stores - no atomics.
__global__ __launch_bounds__(256, 2)
void gemm_w2_kernel(const _Float16* __restrict__ acts,
                    const _Float16* __restrict__ actr,
                    const _Float16* __restrict__ sw2,
                    const _Float16* __restrict__ rw2,
                    float* __restrict__ out,
                    float* __restrict__ zr,
                    const int* __restrict__ cnt,
                    const int* __restrict__ poff) {
    int z = blockIdx.z;
    const _Float16 *srcA, *w;
    float* dst;
    if (z == EE) {
        srcA = acts + (size_t)blockIdx.y * BM * FF;
        w = sw2;
        dst = out + (size_t)blockIdx.y * BM * DD;
    } else {
        int c = cnt[z];
        int mloc = blockIdx.y * BM;
        if (mloc >= c) return;
        int rb = poff[z] + mloc;
        srcA = actr + (size_t)rb * FF;
        w = rw2 + (size_t)z * DD * FF;
        dst = zr + (size_t)rb * DD;
    }
    int n_base = blockIdx.x * 256;

    __shared__ _Float16 lds[(128 + 256) * BK];  // A | B = 48 KB

    const _Float16* srcB = w + (size_t)n_base * FF;

    int lane = threadIdx.x & 63;
    int wv = threadIdx.x >> 6;
    int wm = (wv >> 1) * 64;
    int wn = (wv & 1) * 128;
    int quad = lane >> 4;
    int l15 = lane & 15;
    int srow = lane >> 3;
    int sk = ((lane & 7) ^ srow) * 8;

    f32x4 acc[4][8];
    f32x4 z4 = {0.f, 0.f, 0.f, 0.f};
#pragma unroll
    for (int m = 0; m < 4; m++)
#pragma unroll
        for (int n = 0; n < 8; n++) acc[m][n] = z4;

    for (int kt = 0; kt < FF / BK; ++kt) {       // 32 iterations
        int k0 = kt * BK;
        // 48 chunks of 1 KB (A:0-15, B:16-47); wave wv takes j*4+wv
#pragma unroll
        for (int j = 0; j < 12; ++j) {
            int c = j * 4 + wv;
            const _Float16* src;
            if (c < 16) {
                int r = c * 8 + srow;
                src = srcA + (size_t)r * FF + k0 + sk;
            } else {
                int r = (c - 16) * 8 + srow;
                src = srcB + (size_t)r * FF + k0 + sk;
            }
            gld_lds16(src, &lds[c * 512]);
        }
        __syncthreads();

#pragma unroll
        for (int ks = 0; ks < 2; ++ks) {
            half8 a[4], b[8];
#pragma unroll
            for (int m = 0; m < 4; m++) {
                int ra = wm + m * 16 + l15;
                a[m] = *(const half8*)(&lds[ra * BK + (((ks * 4 + quad) ^ (ra & 7)) * 8)]);
            }
#pragma unroll
            for (int n = 0; n < 8; n++) {
                int rb = wn + n * 16 + l15;
                b[n] = *(const half8*)(&lds[8192 + rb * BK + (((ks * 4 + quad) ^ (rb & 7)) * 8)]);
            }
#pragma unroll
            for (int m = 0; m < 4; m++)
#pragma unroll
                for (int n = 0; n < 8; n++)
                    acc[m][n] = __builtin_amdgcn_mfma_f32_16x16x32_f16(a[m], b[n], acc[m][n], 0, 0, 0);
        }
        __syncthreads();
    }

#pragma unroll
    for (int m = 0; m < 4; m++)
#pragma unroll
        for (int n = 0; n < 8; n++)
#pragma unroll
            for (int r = 0; r < 4; r++) {
                int row = wm + m * 16 + quad * 4 + r;
                int col = n_base + wn + n * 16 + l15;
                dst[(size_t)row * DD + col] = acc[m][n][r];
            }
}

// out[t] += zr[slot0(t)] + zr[slot1(t)]  (each token has exactly 2 slots)
__global__ void combine_kernel(const int4* __restrict__ meta,
                               const int* __restrict__ poff,
                               const float* __restrict__ zr,
                               float* __restrict__ out) {
    int t = blockIdx.x;
    int4 m = meta[t];
    const float* z0 = zr + (size_t)(poff[m.x] + m.y) * DD;
    const float* z1 = zr + (size_t)(poff[m.z] + m.w) * DD;
    float* o = out + (size_t)t * DD;
    for (int d = threadIdx.x * 4; d < DD; d += 1024) {
        float4 a = *(const float4*)(o + d);
        float4 u = *(const float4*)(z0 + d);
        float4 v = *(const float4*)(z1 + d);
        a.x += u.x + v.x; a.y += u.y + v.y;
        a.z += u.z + v.z; a.w += u.w + v.w;
        *(float4*)(o + d) = a;
    }
}

// ---------------- launch ----------------

extern "C" void kernel_launch(void* const* d_in, const int* in_sizes, int n_in,
                              void* d_out, int out_size, void* d_ws, size_t ws_size,
                              hipStream_t stream) {
    const float* x     = (const float*)d_in[0];   // 4096 x 2048
    const float* rDE   = (const float*)d_in[1];   // 2048 x 8
    const float* sw13  = (const float*)d_in[2];   // 4096 x 2048
    const float* sw2   = (const float*)d_in[3];   // 2048 x 2048
    const float* rw13  = (const float*)d_in[4];   // 8 x 4096 x 2048
    const float* rw2   = (const float*)d_in[5];   // 8 x 2048 x 2048
    float* out = (float*)d_out;

    char* ws = (char*)d_ws;
    size_t off = 0;
    auto alloc = [&](size_t bytes) {
        char* p = ws + off;
        off += (bytes + 255) & ~(size_t)255;
        return p;
    };
    _Float16* xh    = (_Float16*)alloc((size_t)TT * DD * 2);
    _Float16* sw13h = (_Float16*)alloc((size_t)2 * FF * DD * 2);
    _Float16* sw2h  = (_Float16*)alloc((size_t)DD * FF * 2);
    _Float16* rw13h = (_Float16*)alloc((size_t)EE * 2 * FF * DD * 2);
    _Float16* rw2h  = (_Float16*)alloc((size_t)EE * DD * FF * 2);
    _Float16* acts  = (_Float16*)alloc((size_t)TT * FF * 2);
    _Float16* actr  = (_Float16*)alloc((size_t)MAXPAD * FF * 2);
    int* cnt        = (int*)alloc(EE * 4);
    int* poff       = (int*)alloc((EE + 1) * 4);
    int* tok_list   = (int*)alloc((size_t)EE * TT * 4);
    float* gate_list= (float*)alloc((size_t)EE * TT * 4);
    int4* meta      = (int4*)alloc((size_t)TT * 16);
    // gath (fp16, 37.75 MB) and zr (fp32, 75.5 MB) share storage: gath's
    // lifetime (gather -> w13) ends before zr's begins (w2 -> combine),
    // enforced by stream order.  zr = gath region + one extra gath-size span.
    _Float16* gath  = (_Float16*)alloc((size_t)MAXPAD * DD * 2);
    alloc((size_t)MAXPAD * DD * 2);               // zr upper half
    float* zr = (float*)gath;

    zero_cnt_kernel<<<1, 64, 0, stream>>>(cnt);

    // fp32 -> fp16 conversions
    auto cvt = [&](const float* s, _Float16* d, int n) {
        cvt_f32_f16_kernel<<<(n / 4 + 255) / 256, 256, 0, stream>>>(s, d, n);
    };
    cvt(x,    xh,    TT * DD);
    cvt(sw13, sw13h, 2 * FF * DD);
    cvt(sw2,  sw2h,  DD * FF);
    cvt(rw13, rw13h, EE * 2 * FF * DD);
    cvt(rw2,  rw2h,  EE * DD * FF);

    router_topk_kernel<<<TT, 256, 0, stream>>>(x, rDE, cnt, tok_list, gate_list, meta);
    scan_offsets_kernel<<<1, 64, 0, stream>>>(cnt, poff);
    gather_rows_kernel<<<MAXPAD, 256, 0, stream>>>(x, cnt, poff, tok_list, gate_list, gath);

    // all w13 (8 routed z-slices with early exit + shared at z=EE)
    gemm_w13_kernel<<<dim3(FF / 128, TT / 128, EE + 1), 256, 0, stream>>>(
        xh, gath, sw13h, rw13h, acts, actr, cnt, poff);
    // all w2 (routed -> zr slots, shared -> out), no atomics
    gemm_w2_kernel<<<dim3(DD / 256, TT / 128, EE + 1), 256, 0, stream>>>(
        acts, actr, sw2h, rw2h, out, zr, cnt, poff);
    // out += routed contributions
    combine_kernel<<<TT, 256, 0, stream>>>(meta, poff, zr, out);
}